// Round 4
// baseline (4319.880 us; speedup 1.0000x reference)
//
#include <hip/hip_runtime.h>

#define LRELU(x) ((x) >= 0.0f ? (x) : 0.2f * (x))

typedef __attribute__((ext_vector_type(8))) short short8;
typedef __attribute__((ext_vector_type(4))) float f32x4;

__device__ __forceinline__ unsigned short f2bf(float f) {
    union { float f; unsigned int u; } v; v.f = f;
    unsigned int u = v.u;
    u += 0x7FFFu + ((u >> 16) & 1u);   // round-to-nearest-even
    return (unsigned short)(u >> 16);
}

__device__ __forceinline__ float bf2f(unsigned short u) {
    union { unsigned int u; float f; } v; v.u = ((unsigned int)u) << 16;
    return v.f;
}

// ---------------------------------------------------------------------------
// K1: node attention tables: fc = feat@W_prop, as = feat@W_attn_src,
//     ad = feat@W_attn_dst   (each [N,8])
// ---------------------------------------------------------------------------
__global__ __launch_bounds__(256) void k_node_tables(
    const float* __restrict__ feat,
    const float* __restrict__ Wp, const float* __restrict__ Was,
    const float* __restrict__ Wad,
    float* __restrict__ fc, float* __restrict__ as_t, float* __restrict__ ad_t,
    int N)
{
    __shared__ float Wl[3 * 2048];  // 3 x [256][8]
    for (int i = threadIdx.x; i < 3 * 2048; i += 256) {
        float v;
        if (i < 2048)      v = Wp[i];
        else if (i < 4096) v = Was[i - 2048];
        else               v = Wad[i - 4096];
        Wl[i] = v;
    }
    __syncthreads();
    int gid = blockIdx.x * 256 + threadIdx.x;
    int n = gid >> 3, h = gid & 7;
    if (n >= N) return;
    const float4* f4 = (const float4*)(feat + (size_t)n * 256);
    float aP = 0.f, aS = 0.f, aD = 0.f;
#pragma unroll 8
    for (int k4 = 0; k4 < 64; ++k4) {
        float4 f = f4[k4];
        int b = k4 * 32 + h;
        aP += f.x * Wl[b]        + f.y * Wl[b + 8]        + f.z * Wl[b + 16]        + f.w * Wl[b + 24];
        aS += f.x * Wl[2048 + b] + f.y * Wl[2048 + b + 8] + f.z * Wl[2048 + b + 16] + f.w * Wl[2048 + b + 24];
        aD += f.x * Wl[4096 + b] + f.y * Wl[4096 + b + 8] + f.z * Wl[4096 + b + 16] + f.w * Wl[4096 + b + 24];
    }
    fc[gid] = aP; as_t[gid] = aS; ad_t[gid] = aD;
}

// ---------------------------------------------------------------------------
// Pass 1: one THREAD per edge, all 8 heads in registers.
//   ex[h] = exp(leaky(as[s][h] + ad[d][h] + feat_edge[e]@We[:,h]))
//   cache exd row (bf16x8, one 16B store), fp32 atomics into sum tables.
// ---------------------------------------------------------------------------
__global__ __launch_bounds__(256) void k_edge1(
    const float* __restrict__ feat_edge,
    const int* __restrict__ src, const int* __restrict__ dst,
    const float* __restrict__ We,
    const float* __restrict__ as_t, const float* __restrict__ ad_t,
    float* __restrict__ sum_dst, float* __restrict__ sum_src,
    unsigned short* __restrict__ exd, int E)
{
    __shared__ float Wl[128];   // [k:16][h:8]
    if (threadIdx.x < 128) Wl[threadIdx.x] = We[threadIdx.x];
    __syncthreads();
    int e = blockIdx.x * 256 + threadIdx.x;
    if (e >= E) return;
    int s = src[e], d = dst[e];

    const float4* fe = (const float4*)(feat_edge + (size_t)e * 16);
    float4 f0 = fe[0], f1 = fe[1], f2 = fe[2], f3 = fe[3];
    float fv[16] = { f0.x, f0.y, f0.z, f0.w, f1.x, f1.y, f1.z, f1.w,
                     f2.x, f2.y, f2.z, f2.w, f3.x, f3.y, f3.z, f3.w };

    const float4* asp = (const float4*)(as_t + (size_t)s * 8);
    float4 a0 = asp[0], a1 = asp[1];
    const float4* adp = (const float4*)(ad_t + (size_t)d * 8);
    float4 b0 = adp[0], b1 = adp[1];
    float asr[8] = { a0.x, a0.y, a0.z, a0.w, a1.x, a1.y, a1.z, a1.w };
    float adr[8] = { b0.x, b0.y, b0.z, b0.w, b1.x, b1.y, b1.z, b1.w };

    short8 exrow;
#pragma unroll
    for (int h = 0; h < 8; ++h) {
        float ae = 0.f;
#pragma unroll
        for (int k = 0; k < 16; ++k)
            ae += fv[k] * Wl[k * 8 + h];
        float ev = asr[h] + adr[h] + ae;
        ev = LRELU(ev);
        float ex = __expf(ev);
        exrow[h] = (short)f2bf(ex);
        atomicAdd(&sum_dst[(size_t)d * 8 + h], ex);
        atomicAdd(&sum_src[(size_t)s * 8 + h], ex);
    }
    *(short8*)&exd[(size_t)e * 8] = exrow;
}

// ---------------------------------------------------------------------------
// Pass 2: one thread per edge; reload cached ex row, normalize (dual softmax,
// geometric mean), accumulate messages in fp32.
// ---------------------------------------------------------------------------
__global__ __launch_bounds__(256) void k_edge2(
    const unsigned short* __restrict__ exd,
    const int* __restrict__ src, const int* __restrict__ dst,
    const float* __restrict__ sum_dst, const float* __restrict__ sum_src,
    const float* __restrict__ fc, float* __restrict__ msg, int E)
{
    int e = blockIdx.x * 256 + threadIdx.x;
    if (e >= E) return;
    int s = src[e], d = dst[e];

    short8 exrow = *(const short8*)&exd[(size_t)e * 8];
    const float4* Sdp = (const float4*)(sum_dst + (size_t)d * 8);
    float4 sd0 = Sdp[0], sd1 = Sdp[1];
    const float4* Ssp = (const float4*)(sum_src + (size_t)s * 8);
    float4 ss0 = Ssp[0], ss1 = Ssp[1];
    const float4* fcp = (const float4*)(fc + (size_t)s * 8);
    float4 fc0 = fcp[0], fc1 = fcp[1];
    float Sd[8] = { sd0.x, sd0.y, sd0.z, sd0.w, sd1.x, sd1.y, sd1.z, sd1.w };
    float Ss[8] = { ss0.x, ss0.y, ss0.z, ss0.w, ss1.x, ss1.y, ss1.z, ss1.w };
    float fcv[8] = { fc0.x, fc0.y, fc0.z, fc0.w, fc1.x, fc1.y, fc1.z, fc1.w };

#pragma unroll
    for (int h = 0; h < 8; ++h) {
        float ex = bf2f((unsigned short)exrow[h]);
        float a_d = fmaxf(ex / Sd[h], 1e-9f);
        float a_s = fmaxf(ex / Ss[h], 1e-9f);
        atomicAdd(&msg[(size_t)d * 8 + h], fcv[h] * sqrtf(a_d * a_s));
    }
}

// ---------------------------------------------------------------------------
// BatchNorm statistics: accum[0..7] = sum_h, accum[8..15] = sumsq_h
// ---------------------------------------------------------------------------
__global__ __launch_bounds__(256) void k_bn_stats(
    const float* __restrict__ msg, float* __restrict__ accum, int N)
{
    __shared__ float s1[8], s2[8];
    if (threadIdx.x < 8) { s1[threadIdx.x] = 0.f; s2[threadIdx.x] = 0.f; }
    __syncthreads();
    int h = threadIdx.x & 7;
    float a1 = 0.f, a2 = 0.f;
    int total = N * 8;
    for (int i = blockIdx.x * 256 + threadIdx.x; i < total; i += gridDim.x * 256) {
        float x = msg[i];
        a1 += x; a2 += x * x;
    }
    atomicAdd(&s1[h], a1);
    atomicAdd(&s2[h], a2);
    __syncthreads();
    if (threadIdx.x < 8) {
        atomicAdd(&accum[threadIdx.x], s1[threadIdx.x]);
        atomicAdd(&accum[8 + threadIdx.x], s2[threadIdx.x]);
    }
}

// ---------------------------------------------------------------------------
// Prep: bf16 weight tables in B-fragment layout [chunk][n:256][k:32]
// ---------------------------------------------------------------------------
__global__ __launch_bounds__(256) void k_prep(
    const float* __restrict__ W1, const float* __restrict__ Wagg,
    const float* __restrict__ W2,
    const float* __restrict__ b_agg, const float* __restrict__ b1,
    const float* __restrict__ b2,
    unsigned short* __restrict__ B1t, unsigned short* __restrict__ B2t,
    float* __restrict__ bias1, float* __restrict__ bias2)
{
    int idx = blockIdx.x * 256 + threadIdx.x;
    if (idx < 73728) {                       // 9 chunks * 8192
        int c = idx >> 13, rem = idx & 8191;
        int n = rem >> 5, k = rem & 31;
        float v;
        if (c < 8) v = W1[(c * 32 + k) * 256 + n];
        else       v = (k < 8) ? Wagg[k * 256 + n] : 0.f;
        B1t[idx] = f2bf(v);
    } else if (idx < 139264) {               // + 8 chunks * 8192
        int j = idx - 73728;
        int c = j >> 13, rem = j & 8191;
        int n = rem >> 5, k = rem & 31;
        B2t[j] = f2bf(W2[(c * 32 + k) * 256 + n]);
    } else if (idx < 139520) {
        int n = idx - 139264;
        bias1[n] = b_agg[n] + b1[n];
    } else if (idx < 139776) {
        int n = idx - 139520;
        bias2[n] = b2[n];
    }
}

// ---------------------------------------------------------------------------
// Fused MFMA kernel (BN folded into h staging):
//   h   = BN(msg) * gamma + beta                [from accum stats]
//   rst = LRELU( feat@W1 + h@Wagg + bias1 )     [GEMM1, K=288 bf16 MFMA]
//   out = rst@W2 + bias2                        [GEMM2, K=256, rst in LDS]
// ---------------------------------------------------------------------------
#define ASTRIDE 296   // 288 K + 8 pad (bf16) -> 2-way (free) LDS conflicts

__global__ __launch_bounds__(256, 2) void k_fused_apply(
    const float* __restrict__ feat, const float* __restrict__ msg,
    const float* __restrict__ accum,
    const float* __restrict__ gamma, const float* __restrict__ beta,
    const unsigned short* __restrict__ B1t,
    const unsigned short* __restrict__ B2t,
    const float* __restrict__ bias1, const float* __restrict__ bias2,
    float* __restrict__ out, int N)
{
    __shared__ __align__(16) unsigned short As[64 * ASTRIDE];
    __shared__ __align__(16) unsigned short Bs[8192];

    int tid = threadIdx.x;
    int row0 = blockIdx.x * 64;

#pragma unroll
    for (int t = 0; t < 16; ++t) {
        int i = tid + t * 256;
        int r = i >> 6, k4 = i & 63;
        float4 f = make_float4(0.f, 0.f, 0.f, 0.f);
        if (row0 + r < N)
            f = ((const float4*)(feat + (size_t)(row0 + r) * 256))[k4];
        ushort4 b;
        b.x = f2bf(f.x); b.y = f2bf(f.y); b.z = f2bf(f.z); b.w = f2bf(f.w);
        *(ushort4*)&As[r * ASTRIDE + k4 * 4] = b;
    }
    // h staging with BN applied on the fly
#pragma unroll
    for (int t = 0; t < 8; ++t) {
        int e = tid + t * 256;
        int r = e >> 5, c = e & 31;
        float v = 0.f;
        if (c < 8 && row0 + r < N) {
            float invN = 1.0f / (float)N;
            float mu = accum[c] * invN;
            float var = accum[8 + c] * invN - mu * mu;
            float rstd = rsqrtf(var + 1e-5f);
            v = (msg[(size_t)(row0 + r) * 8 + c] - mu) * rstd * gamma[c] + beta[c];
        }
        As[r * ASTRIDE + 256 + c] = f2bf(v);
    }

    int wave = tid >> 6;
    int lane = tid & 63;
    int n16  = lane & 15;
    int quad = lane >> 4;
    int col0 = wave * 64;

    f32x4 acc[4][4];
#pragma unroll
    for (int rt = 0; rt < 4; ++rt)
#pragma unroll
        for (int ct = 0; ct < 4; ++ct)
            acc[rt][ct] = (f32x4){0.f, 0.f, 0.f, 0.f};

    for (int kc = 0; kc < 9; ++kc) {
        __syncthreads();
#pragma unroll
        for (int t = 0; t < 4; ++t) {
            int i = tid + t * 256;
            ((float4*)Bs)[i] = ((const float4*)(B1t + kc * 8192))[i];
        }
        __syncthreads();
        int kbase = kc * 32;
        short8 af[4], bf[4];
#pragma unroll
        for (int rt = 0; rt < 4; ++rt)
            af[rt] = *(const short8*)&As[(rt * 16 + n16) * ASTRIDE + kbase + quad * 8];
#pragma unroll
        for (int ct = 0; ct < 4; ++ct)
            bf[ct] = *(const short8*)&Bs[(col0 + ct * 16 + n16) * 32 + quad * 8];
#pragma unroll
        for (int rt = 0; rt < 4; ++rt)
#pragma unroll
            for (int ct = 0; ct < 4; ++ct)
                acc[rt][ct] = __builtin_amdgcn_mfma_f32_16x16x32_bf16(
                    af[rt], bf[ct], acc[rt][ct], 0, 0, 0);
    }

    float bi[4];
#pragma unroll
    for (int ct = 0; ct < 4; ++ct) bi[ct] = bias1[col0 + ct * 16 + n16];
    __syncthreads();
#pragma unroll
    for (int rt = 0; rt < 4; ++rt)
#pragma unroll
        for (int ct = 0; ct < 4; ++ct)
#pragma unroll
            for (int r = 0; r < 4; ++r) {
                float v = acc[rt][ct][r] + bi[ct];
                v = LRELU(v);
                int row = rt * 16 + quad * 4 + r;
                int col = col0 + ct * 16 + n16;
                As[row * ASTRIDE + col] = f2bf(v);
            }

#pragma unroll
    for (int rt = 0; rt < 4; ++rt)
#pragma unroll
        for (int ct = 0; ct < 4; ++ct)
            acc[rt][ct] = (f32x4){0.f, 0.f, 0.f, 0.f};

    for (int kc = 0; kc < 8; ++kc) {
        __syncthreads();
#pragma unroll
        for (int t = 0; t < 4; ++t) {
            int i = tid + t * 256;
            ((float4*)Bs)[i] = ((const float4*)(B2t + kc * 8192))[i];
        }
        __syncthreads();
        int kbase = kc * 32;
        short8 af[4], bf[4];
#pragma unroll
        for (int rt = 0; rt < 4; ++rt)
            af[rt] = *(const short8*)&As[(rt * 16 + n16) * ASTRIDE + kbase + quad * 8];
#pragma unroll
        for (int ct = 0; ct < 4; ++ct)
            bf[ct] = *(const short8*)&Bs[(col0 + ct * 16 + n16) * 32 + quad * 8];
#pragma unroll
        for (int rt = 0; rt < 4; ++rt)
#pragma unroll
            for (int ct = 0; ct < 4; ++ct)
                acc[rt][ct] = __builtin_amdgcn_mfma_f32_16x16x32_bf16(
                    af[rt], bf[ct], acc[rt][ct], 0, 0, 0);
    }

    float bi2[4];
#pragma unroll
    for (int ct = 0; ct < 4; ++ct) bi2[ct] = bias2[col0 + ct * 16 + n16];
#pragma unroll
    for (int rt = 0; rt < 4; ++rt)
#pragma unroll
        for (int r = 0; r < 4; ++r) {
            int row = row0 + rt * 16 + quad * 4 + r;
            if (row < N) {
#pragma unroll
                for (int ct = 0; ct < 4; ++ct) {
                    int col = col0 + ct * 16 + n16;
                    out[(size_t)row * 256 + col] = acc[rt][ct][r] + bi2[ct];
                }
            }
        }
}

// ---------------------------------------------------------------------------
extern "C" void kernel_launch(void* const* d_in, const int* in_sizes, int n_in,
                              void* d_out, int out_size, void* d_ws, size_t ws_size,
                              hipStream_t stream)
{
    const float* feat      = (const float*)d_in[0];
    const float* feat_edge = (const float*)d_in[1];
    const int*   src       = (const int*)d_in[2];
    const int*   dst       = (const int*)d_in[3];
    const float* W_prop    = (const float*)d_in[4];
    const float* W_as      = (const float*)d_in[5];
    const float* W_ad      = (const float*)d_in[6];
    const float* W_edge    = (const float*)d_in[7];
    const float* bn_gamma  = (const float*)d_in[8];
    const float* bn_beta   = (const float*)d_in[9];
    const float* W_agg     = (const float*)d_in[10];
    const float* b_agg     = (const float*)d_in[11];
    const float* W1        = (const float*)d_in[12];
    const float* b1        = (const float*)d_in[13];
    const float* W2        = (const float*)d_in[14];
    const float* b2        = (const float*)d_in[15];
    float* out = (float*)d_out;

    int N = in_sizes[0] / 256;
    int E = in_sizes[2];
    int N8 = N * 8;

    // ---- workspace layout (64B-aligned regions); zeroed prefix first ----
    char* base = (char*)d_ws;
    size_t o = 0;
    auto take = [&](size_t bytes) -> char* {
        char* p = base + o;
        o = (o + bytes + 63) & ~(size_t)63;
        return p;
    };
    float* sum_dst = (float*)take((size_t)N8 * sizeof(float));
    float* sum_src = (float*)take((size_t)N8 * sizeof(float));
    float* msg     = (float*)take((size_t)N8 * sizeof(float));
    float* accum   = (float*)take(16 * sizeof(float));
    size_t zero_bytes = o;                       // everything above needs zeroing
    float* fc    = (float*)take((size_t)N8 * sizeof(float));
    float* as_t  = (float*)take((size_t)N8 * sizeof(float));
    float* ad_t  = (float*)take((size_t)N8 * sizeof(float));
    float* bias1 = (float*)take(256 * sizeof(float));
    float* bias2 = (float*)take(256 * sizeof(float));
    unsigned short* B1t = (unsigned short*)take(73728 * sizeof(unsigned short));
    unsigned short* B2t = (unsigned short*)take(65536 * sizeof(unsigned short));
    unsigned short* exd = (unsigned short*)take((size_t)E * 8 * sizeof(unsigned short));
    (void)ws_size;

    hipMemsetAsync(d_ws, 0, zero_bytes, stream);

    int gridN8 = (N8 + 255) / 256;
    int gridE  = (E + 255) / 256;
    int gridF  = (N + 63) / 64;

    k_prep<<<546, 256, 0, stream>>>(W1, W_agg, W2, b_agg, b1, b2,
                                    B1t, B2t, bias1, bias2);
    k_node_tables<<<gridN8, 256, 0, stream>>>(feat, W_prop, W_as, W_ad,
                                              fc, as_t, ad_t, N);
    k_edge1<<<gridE, 256, 0, stream>>>(feat_edge, src, dst, W_edge,
                                       as_t, ad_t, sum_dst, sum_src, exd, E);
    k_edge2<<<gridE, 256, 0, stream>>>(exd, src, dst, sum_dst, sum_src,
                                       fc, msg, E);
    k_bn_stats<<<512, 256, 0, stream>>>(msg, accum, N);
    k_fused_apply<<<gridF, 256, 0, stream>>>(feat, msg, accum, bn_gamma, bn_beta,
                                             B1t, B2t, bias1, bias2, out, N);
}

// Round 5
// 1026.796 us; speedup vs baseline: 4.2071x; 4.2071x over previous
//
#include <hip/hip_runtime.h>

#define LRELU(x) ((x) >= 0.0f ? (x) : 0.2f * (x))

typedef __attribute__((ext_vector_type(8))) short short8;
typedef __attribute__((ext_vector_type(4))) float f32x4;

__device__ __forceinline__ unsigned short f2bf(float f) {
    union { float f; unsigned int u; } v; v.f = f;
    unsigned int u = v.u;
    u += 0x7FFFu + ((u >> 16) & 1u);   // round-to-nearest-even
    return (unsigned short)(u >> 16);
}

__device__ __forceinline__ float bf2f(unsigned short u) {
    union { unsigned int u; float f; } v; v.u = ((unsigned int)u) << 16;
    return v.f;
}

// Physical XCD id (0..7 on MI355X) — wave-uniform, all waves of a WG share a CU/XCD.
__device__ __forceinline__ int xcc_id() {
    unsigned x;
    asm("s_getreg_b32 %0, hwreg(HW_REG_XCC_ID)" : "=s"(x));
    return (int)(x & 7);
}

// XCD-local (L2-resolved) fp32 atomic add: workgroup scope keeps it in the
// issuing XCD's TCC; correctness requires all accessors of the address be on
// the same XCD — guaranteed by per-XCD replicas.
__device__ __forceinline__ void l2_atomic_add(float* p, float v) {
    __hip_atomic_fetch_add(p, v, __ATOMIC_RELAXED, __HIP_MEMORY_SCOPE_WORKGROUP);
}

// ---------------------------------------------------------------------------
// K1: node attention tables: fc = feat@W_prop, as = feat@W_attn_src,
//     ad = feat@W_attn_dst   (each [N,8])
// ---------------------------------------------------------------------------
__global__ __launch_bounds__(256) void k_node_tables(
    const float* __restrict__ feat,
    const float* __restrict__ Wp, const float* __restrict__ Was,
    const float* __restrict__ Wad,
    float* __restrict__ fc, float* __restrict__ as_t, float* __restrict__ ad_t,
    int N)
{
    __shared__ float Wl[3 * 2048];  // 3 x [256][8]
    for (int i = threadIdx.x; i < 3 * 2048; i += 256) {
        float v;
        if (i < 2048)      v = Wp[i];
        else if (i < 4096) v = Was[i - 2048];
        else               v = Wad[i - 4096];
        Wl[i] = v;
    }
    __syncthreads();
    int gid = blockIdx.x * 256 + threadIdx.x;
    int n = gid >> 3, h = gid & 7;
    if (n >= N) return;
    const float4* f4 = (const float4*)(feat + (size_t)n * 256);
    float aP = 0.f, aS = 0.f, aD = 0.f;
#pragma unroll 8
    for (int k4 = 0; k4 < 64; ++k4) {
        float4 f = f4[k4];
        int b = k4 * 32 + h;
        aP += f.x * Wl[b]        + f.y * Wl[b + 8]        + f.z * Wl[b + 16]        + f.w * Wl[b + 24];
        aS += f.x * Wl[2048 + b] + f.y * Wl[2048 + b + 8] + f.z * Wl[2048 + b + 16] + f.w * Wl[2048 + b + 24];
        aD += f.x * Wl[4096 + b] + f.y * Wl[4096 + b + 8] + f.z * Wl[4096 + b + 16] + f.w * Wl[4096 + b + 24];
    }
    fc[gid] = aP; as_t[gid] = aS; ad_t[gid] = aD;
}

// ---------------------------------------------------------------------------
// Edge attention value (8 lanes per edge, lane = head)
// ---------------------------------------------------------------------------
__device__ __forceinline__ float edge_ex(
    const float* __restrict__ feat_edge, const float* Wl,
    const float* __restrict__ as_t, const float* __restrict__ ad_t,
    int e, int h, int s, int d)
{
    const float4* fe = (const float4*)(feat_edge + (size_t)e * 16);
    float4 f0 = fe[0], f1 = fe[1], f2 = fe[2], f3 = fe[3];
    float ae = f0.x * Wl[h]      + f0.y * Wl[h + 8]   + f0.z * Wl[h + 16]  + f0.w * Wl[h + 24]
             + f1.x * Wl[h + 32] + f1.y * Wl[h + 40]  + f1.z * Wl[h + 48]  + f1.w * Wl[h + 56]
             + f2.x * Wl[h + 64] + f2.y * Wl[h + 72]  + f2.z * Wl[h + 80]  + f2.w * Wl[h + 88]
             + f3.x * Wl[h + 96] + f3.y * Wl[h + 104] + f3.z * Wl[h + 112] + f3.w * Wl[h + 120];
    float ev = as_t[(size_t)s * 8 + h] + ad_t[(size_t)d * 8 + h] + ae;
    ev = LRELU(ev);
    return __expf(ev);
}

// ---------------------------------------------------------------------------
// Pass 1: ex once per (edge,head); cache bf16 (if exd != null); accumulate
// softmax sums into the THIS-XCD replica via L2-resolved atomics.
//   sdr layout: replica x at sdr + x*2*N8; [0,N8) = sum_dst, [N8,2N8) = sum_src
// ---------------------------------------------------------------------------
__global__ __launch_bounds__(256) void k_edge1(
    const float* __restrict__ feat_edge,
    const int* __restrict__ src, const int* __restrict__ dst,
    const float* __restrict__ We,
    const float* __restrict__ as_t, const float* __restrict__ ad_t,
    float* __restrict__ sdr, unsigned short* __restrict__ exd,
    int E, int N8)
{
    __shared__ float Wl[128];
    if (threadIdx.x < 128) Wl[threadIdx.x] = We[threadIdx.x];
    __syncthreads();
    int gid = blockIdx.x * 256 + threadIdx.x;
    int e = gid >> 3, h = gid & 7;
    if (e >= E) return;
    int s = src[e], d = dst[e];
    float ex = edge_ex(feat_edge, Wl, as_t, ad_t, e, h, s, d);
    if (exd) exd[gid] = f2bf(ex);
    float* rep = sdr + (size_t)xcc_id() * 2 * (size_t)N8;
    l2_atomic_add(rep + (size_t)d * 8 + h, ex);
    l2_atomic_add(rep + (size_t)N8 + (size_t)s * 8 + h, ex);
}

// ---------------------------------------------------------------------------
// Reduce 8 replicas -> sums[2*N8]
// ---------------------------------------------------------------------------
__global__ __launch_bounds__(256) void k_reduce_sums(
    const float* __restrict__ sdr, float* __restrict__ sums, int total)
{
    int i = blockIdx.x * 256 + threadIdx.x;
    if (i >= total) return;
    float a = 0.f;
#pragma unroll
    for (int x = 0; x < 8; ++x) a += sdr[(size_t)x * total + i];
    sums[i] = a;
}

// ---------------------------------------------------------------------------
// Pass 2: normalize (dual softmax, geometric mean), accumulate msg into the
// THIS-XCD replica (msgr + x*N8). ex from cache (or recompute if exd null).
// ---------------------------------------------------------------------------
__global__ __launch_bounds__(256) void k_edge2(
    const unsigned short* __restrict__ exd,
    const float* __restrict__ feat_edge, const float* __restrict__ We,
    const int* __restrict__ src, const int* __restrict__ dst,
    const float* __restrict__ sums,
    const float* __restrict__ as_t, const float* __restrict__ ad_t,
    const float* __restrict__ fc, float* __restrict__ msgr,
    int E, int N8)
{
    __shared__ float Wl[128];
    if (threadIdx.x < 128) Wl[threadIdx.x] = We[threadIdx.x];
    __syncthreads();
    int gid = blockIdx.x * 256 + threadIdx.x;
    int e = gid >> 3, h = gid & 7;
    if (e >= E) return;
    int s = src[e], d = dst[e];
    float ex = exd ? bf2f(exd[gid])
                   : edge_ex(feat_edge, Wl, as_t, ad_t, e, h, s, d);
    float Sd = sums[(size_t)d * 8 + h];
    float Ss = sums[(size_t)N8 + (size_t)s * 8 + h];
    float a_d = fmaxf(ex / Sd, 1e-9f);
    float a_s = fmaxf(ex / Ss, 1e-9f);
    float m = fc[(size_t)s * 8 + h] * sqrtf(a_d * a_s);
    l2_atomic_add(msgr + (size_t)xcc_id() * (size_t)N8 + (size_t)d * 8 + h, m);
}

// ---------------------------------------------------------------------------
// Reduce msg replicas + BatchNorm statistics in one pass.
//   accum[0..7] = sum_h, accum[8..15] = sumsq_h
// ---------------------------------------------------------------------------
__global__ __launch_bounds__(256) void k_reduce_msg_bn(
    const float* __restrict__ msgr, float* __restrict__ msg,
    float* __restrict__ accum, int N8)
{
    __shared__ float s1[8], s2[8];
    if (threadIdx.x < 8) { s1[threadIdx.x] = 0.f; s2[threadIdx.x] = 0.f; }
    __syncthreads();
    int h = threadIdx.x & 7;
    float a1 = 0.f, a2 = 0.f;
    for (int i = blockIdx.x * 256 + threadIdx.x; i < N8; i += gridDim.x * 256) {
        float v = 0.f;
#pragma unroll
        for (int x = 0; x < 8; ++x) v += msgr[(size_t)x * N8 + i];
        msg[i] = v;
        a1 += v; a2 += v * v;
    }
    atomicAdd(&s1[h], a1);
    atomicAdd(&s2[h], a2);
    __syncthreads();
    if (threadIdx.x < 8) {
        atomicAdd(&accum[threadIdx.x], s1[threadIdx.x]);
        atomicAdd(&accum[8 + threadIdx.x], s2[threadIdx.x]);
    }
}

// ---------------------------------------------------------------------------
// Prep: bf16 weight tables in B-fragment layout [chunk][n:256][k:32]
// ---------------------------------------------------------------------------
__global__ __launch_bounds__(256) void k_prep(
    const float* __restrict__ W1, const float* __restrict__ Wagg,
    const float* __restrict__ W2,
    const float* __restrict__ b_agg, const float* __restrict__ b1,
    const float* __restrict__ b2,
    unsigned short* __restrict__ B1t, unsigned short* __restrict__ B2t,
    float* __restrict__ bias1, float* __restrict__ bias2)
{
    int idx = blockIdx.x * 256 + threadIdx.x;
    if (idx < 73728) {                       // 9 chunks * 8192
        int c = idx >> 13, rem = idx & 8191;
        int n = rem >> 5, k = rem & 31;
        float v;
        if (c < 8) v = W1[(c * 32 + k) * 256 + n];
        else       v = (k < 8) ? Wagg[k * 256 + n] : 0.f;
        B1t[idx] = f2bf(v);
    } else if (idx < 139264) {               // + 8 chunks * 8192
        int j = idx - 73728;
        int c = j >> 13, rem = j & 8191;
        int n = rem >> 5, k = rem & 31;
        B2t[j] = f2bf(W2[(c * 32 + k) * 256 + n]);
    } else if (idx < 139520) {
        int n = idx - 139264;
        bias1[n] = b_agg[n] + b1[n];
    } else if (idx < 139776) {
        int n = idx - 139520;
        bias2[n] = b2[n];
    }
}

// ---------------------------------------------------------------------------
// Fused MFMA kernel (BN folded into h staging):
//   h   = BN(msg) * gamma + beta                [from accum stats]
//   rst = LRELU( feat@W1 + h@Wagg + bias1 )     [GEMM1, K=288 bf16 MFMA]
//   out = rst@W2 + bias2                        [GEMM2, K=256, rst in LDS]
// ---------------------------------------------------------------------------
#define ASTRIDE 296   // 288 K + 8 pad (bf16) -> 2-way (free) LDS conflicts

__global__ __launch_bounds__(256, 2) void k_fused_apply(
    const float* __restrict__ feat, const float* __restrict__ msg,
    const float* __restrict__ accum,
    const float* __restrict__ gamma, const float* __restrict__ beta,
    const unsigned short* __restrict__ B1t,
    const unsigned short* __restrict__ B2t,
    const float* __restrict__ bias1, const float* __restrict__ bias2,
    float* __restrict__ out, int N)
{
    __shared__ __align__(16) unsigned short As[64 * ASTRIDE];
    __shared__ __align__(16) unsigned short Bs[8192];

    int tid = threadIdx.x;
    int row0 = blockIdx.x * 64;

#pragma unroll
    for (int t = 0; t < 16; ++t) {
        int i = tid + t * 256;
        int r = i >> 6, k4 = i & 63;
        float4 f = make_float4(0.f, 0.f, 0.f, 0.f);
        if (row0 + r < N)
            f = ((const float4*)(feat + (size_t)(row0 + r) * 256))[k4];
        ushort4 b;
        b.x = f2bf(f.x); b.y = f2bf(f.y); b.z = f2bf(f.z); b.w = f2bf(f.w);
        *(ushort4*)&As[r * ASTRIDE + k4 * 4] = b;
    }
    // h staging with BN applied on the fly
#pragma unroll
    for (int t = 0; t < 8; ++t) {
        int e = tid + t * 256;
        int r = e >> 5, c = e & 31;
        float v = 0.f;
        if (c < 8 && row0 + r < N) {
            float invN = 1.0f / (float)N;
            float mu = accum[c] * invN;
            float var = accum[8 + c] * invN - mu * mu;
            float rstd = rsqrtf(var + 1e-5f);
            v = (msg[(size_t)(row0 + r) * 8 + c] - mu) * rstd * gamma[c] + beta[c];
        }
        As[r * ASTRIDE + 256 + c] = f2bf(v);
    }

    int wave = tid >> 6;
    int lane = tid & 63;
    int n16  = lane & 15;
    int quad = lane >> 4;
    int col0 = wave * 64;

    f32x4 acc[4][4];
#pragma unroll
    for (int rt = 0; rt < 4; ++rt)
#pragma unroll
        for (int ct = 0; ct < 4; ++ct)
            acc[rt][ct] = (f32x4){0.f, 0.f, 0.f, 0.f};

    for (int kc = 0; kc < 9; ++kc) {
        __syncthreads();
#pragma unroll
        for (int t = 0; t < 4; ++t) {
            int i = tid + t * 256;
            ((float4*)Bs)[i] = ((const float4*)(B1t + kc * 8192))[i];
        }
        __syncthreads();
        int kbase = kc * 32;
        short8 af[4], bf[4];
#pragma unroll
        for (int rt = 0; rt < 4; ++rt)
            af[rt] = *(const short8*)&As[(rt * 16 + n16) * ASTRIDE + kbase + quad * 8];
#pragma unroll
        for (int ct = 0; ct < 4; ++ct)
            bf[ct] = *(const short8*)&Bs[(col0 + ct * 16 + n16) * 32 + quad * 8];
#pragma unroll
        for (int rt = 0; rt < 4; ++rt)
#pragma unroll
            for (int ct = 0; ct < 4; ++ct)
                acc[rt][ct] = __builtin_amdgcn_mfma_f32_16x16x32_bf16(
                    af[rt], bf[ct], acc[rt][ct], 0, 0, 0);
    }

    float bi[4];
#pragma unroll
    for (int ct = 0; ct < 4; ++ct) bi[ct] = bias1[col0 + ct * 16 + n16];
    __syncthreads();
#pragma unroll
    for (int rt = 0; rt < 4; ++rt)
#pragma unroll
        for (int ct = 0; ct < 4; ++ct)
#pragma unroll
            for (int r = 0; r < 4; ++r) {
                float v = acc[rt][ct][r] + bi[ct];
                v = LRELU(v);
                int row = rt * 16 + quad * 4 + r;
                int col = col0 + ct * 16 + n16;
                As[row * ASTRIDE + col] = f2bf(v);
            }

#pragma unroll
    for (int rt = 0; rt < 4; ++rt)
#pragma unroll
        for (int ct = 0; ct < 4; ++ct)
            acc[rt][ct] = (f32x4){0.f, 0.f, 0.f, 0.f};

    for (int kc = 0; kc < 8; ++kc) {
        __syncthreads();
#pragma unroll
        for (int t = 0; t < 4; ++t) {
            int i = tid + t * 256;
            ((float4*)Bs)[i] = ((const float4*)(B2t + kc * 8192))[i];
        }
        __syncthreads();
        int kbase = kc * 32;
        short8 af[4], bf[4];
#pragma unroll
        for (int rt = 0; rt < 4; ++rt)
            af[rt] = *(const short8*)&As[(rt * 16 + n16) * ASTRIDE + kbase + quad * 8];
#pragma unroll
        for (int ct = 0; ct < 4; ++ct)
            bf[ct] = *(const short8*)&Bs[(col0 + ct * 16 + n16) * 32 + quad * 8];
#pragma unroll
        for (int rt = 0; rt < 4; ++rt)
#pragma unroll
            for (int ct = 0; ct < 4; ++ct)
                acc[rt][ct] = __builtin_amdgcn_mfma_f32_16x16x32_bf16(
                    af[rt], bf[ct], acc[rt][ct], 0, 0, 0);
    }

    float bi2[4];
#pragma unroll
    for (int ct = 0; ct < 4; ++ct) bi2[ct] = bias2[col0 + ct * 16 + n16];
#pragma unroll
    for (int rt = 0; rt < 4; ++rt)
#pragma unroll
        for (int r = 0; r < 4; ++r) {
            int row = row0 + rt * 16 + quad * 4 + r;
            if (row < N) {
#pragma unroll
                for (int ct = 0; ct < 4; ++ct) {
                    int col = col0 + ct * 16 + n16;
                    out[(size_t)row * 256 + col] = acc[rt][ct][r] + bi2[ct];
                }
            }
        }
}

// ---------------------------------------------------------------------------
extern "C" void kernel_launch(void* const* d_in, const int* in_sizes, int n_in,
                              void* d_out, int out_size, void* d_ws, size_t ws_size,
                              hipStream_t stream)
{
    const float* feat      = (const float*)d_in[0];
    const float* feat_edge = (const float*)d_in[1];
    const int*   src       = (const int*)d_in[2];
    const int*   dst       = (const int*)d_in[3];
    const float* W_prop    = (const float*)d_in[4];
    const float* W_as      = (const float*)d_in[5];
    const float* W_ad      = (const float*)d_in[6];
    const float* W_edge    = (const float*)d_in[7];
    const float* bn_gamma  = (const float*)d_in[8];
    const float* bn_beta   = (const float*)d_in[9];
    const float* W_agg     = (const float*)d_in[10];
    const float* b_agg     = (const float*)d_in[11];
    const float* W1        = (const float*)d_in[12];
    const float* b1        = (const float*)d_in[13];
    const float* W2        = (const float*)d_in[14];
    const float* b2        = (const float*)d_in[15];
    float* out = (float*)d_out;

    int N = in_sizes[0] / 256;
    int E = in_sizes[2];
    int N8 = N * 8;

    // ---- workspace layout (64B-aligned regions); zeroed prefix first ----
    char* base = (char*)d_ws;
    size_t o = 0;
    auto take = [&](size_t bytes) -> char* {
        char* p = base + o;
        o = (o + bytes + 63) & ~(size_t)63;
        return p;
    };
    float* sdr   = (float*)take((size_t)8 * 2 * N8 * sizeof(float));  // 8 replicas [sum_dst|sum_src]
    float* msgr  = (float*)take((size_t)8 * N8 * sizeof(float));      // 8 replicas msg
    float* accum = (float*)take(16 * sizeof(float));
    size_t zero_bytes = o;                       // everything above needs zeroing
    float* sums  = (float*)take((size_t)2 * N8 * sizeof(float));
    float* msg   = (float*)take((size_t)N8 * sizeof(float));
    float* fc    = (float*)take((size_t)N8 * sizeof(float));
    float* as_t  = (float*)take((size_t)N8 * sizeof(float));
    float* ad_t  = (float*)take((size_t)N8 * sizeof(float));
    float* bias1 = (float*)take(256 * sizeof(float));
    float* bias2 = (float*)take(256 * sizeof(float));
    unsigned short* B1t = (unsigned short*)take(73728 * sizeof(unsigned short));
    unsigned short* B2t = (unsigned short*)take(65536 * sizeof(unsigned short));
    size_t need_noexd = o;
    unsigned short* exd = (unsigned short*)take((size_t)E * 8 * sizeof(unsigned short));
    size_t need_full = o;

    // exd cache only if the workspace holds it (round-2 run proved >= ~124 MB)
    if (ws_size < need_full) exd = nullptr;
    (void)need_noexd;

    hipMemsetAsync(d_ws, 0, zero_bytes, stream);

    int gridN8 = (N8 + 255) / 256;
    int gridE8 = (E * 8 + 255) / 256;
    int gridS  = (2 * N8 + 255) / 256;
    int gridF  = (N + 63) / 64;

    k_prep<<<546, 256, 0, stream>>>(W1, W_agg, W2, b_agg, b1, b2,
                                    B1t, B2t, bias1, bias2);
    k_node_tables<<<gridN8, 256, 0, stream>>>(feat, W_prop, W_as, W_ad,
                                              fc, as_t, ad_t, N);
    k_edge1<<<gridE8, 256, 0, stream>>>(feat_edge, src, dst, W_edge,
                                        as_t, ad_t, sdr, exd, E, N8);
    k_reduce_sums<<<gridS, 256, 0, stream>>>(sdr, sums, 2 * N8);
    k_edge2<<<gridE8, 256, 0, stream>>>(exd, feat_edge, W_edge, src, dst,
                                        sums, as_t, ad_t, fc, msgr, E, N8);
    k_reduce_msg_bn<<<512, 256, 0, stream>>>(msgr, msg, accum, N8);
    k_fused_apply<<<gridF, 256, 0, stream>>>(feat, msg, accum, bn_gamma, bn_beta,
                                             B1t, B2t, bias1, bias2, out, N);
}

// Round 6
// 970.299 us; speedup vs baseline: 4.4521x; 1.0582x over previous
//
#include <hip/hip_runtime.h>

#define LRELU(x) ((x) >= 0.0f ? (x) : 0.2f * (x))

typedef __attribute__((ext_vector_type(8))) short short8;
typedef __attribute__((ext_vector_type(4))) float f32x4;

__device__ __forceinline__ unsigned short f2bf(float f) {
    union { float f; unsigned int u; } v; v.f = f;
    unsigned int u = v.u;
    u += 0x7FFFu + ((u >> 16) & 1u);   // round-to-nearest-even
    return (unsigned short)(u >> 16);
}

__device__ __forceinline__ float bf2f(unsigned short u) {
    union { unsigned int u; float f; } v; v.u = ((unsigned int)u) << 16;
    return v.f;
}

// ---------------------------------------------------------------------------
// Merged K1: blocks [0, gridN8) compute node tables (fc/as/ad = feat @ W*),
// blocks [gridN8, gridN8+546) build bf16 weight tables + biases (old k_prep).
// ---------------------------------------------------------------------------
__global__ __launch_bounds__(256) void k_nodeprep(
    const float* __restrict__ feat,
    const float* __restrict__ Wp, const float* __restrict__ Was,
    const float* __restrict__ Wad,
    float* __restrict__ fc, float* __restrict__ as_t, float* __restrict__ ad_t,
    int N, int gridN8,
    const float* __restrict__ W1, const float* __restrict__ Wagg,
    const float* __restrict__ W2,
    const float* __restrict__ b_agg, const float* __restrict__ b1,
    const float* __restrict__ b2,
    unsigned short* __restrict__ B1t, unsigned short* __restrict__ B2t,
    float* __restrict__ bias1, float* __restrict__ bias2)
{
    if ((int)blockIdx.x >= gridN8) {
        // ---- prep part ----
        int idx = (blockIdx.x - gridN8) * 256 + threadIdx.x;
        if (idx < 73728) {                       // 9 chunks * 8192
            int c = idx >> 13, rem = idx & 8191;
            int n = rem >> 5, k = rem & 31;
            float v;
            if (c < 8) v = W1[(c * 32 + k) * 256 + n];
            else       v = (k < 8) ? Wagg[k * 256 + n] : 0.f;
            B1t[idx] = f2bf(v);
        } else if (idx < 139264) {               // + 8 chunks * 8192
            int j = idx - 73728;
            int c = j >> 13, rem = j & 8191;
            int n = rem >> 5, k = rem & 31;
            B2t[j] = f2bf(W2[(c * 32 + k) * 256 + n]);
        } else if (idx < 139520) {
            int n = idx - 139264;
            bias1[n] = b_agg[n] + b1[n];
        } else if (idx < 139776) {
            int n = idx - 139520;
            bias2[n] = b2[n];
        }
        return;
    }
    // ---- node-tables part ----
    __shared__ float Wl[3 * 2048];  // 3 x [256][8]
    for (int i = threadIdx.x; i < 3 * 2048; i += 256) {
        float v;
        if (i < 2048)      v = Wp[i];
        else if (i < 4096) v = Was[i - 2048];
        else               v = Wad[i - 4096];
        Wl[i] = v;
    }
    __syncthreads();
    int gid = blockIdx.x * 256 + threadIdx.x;
    int n = gid >> 3, h = gid & 7;
    if (n >= N) return;
    const float4* f4 = (const float4*)(feat + (size_t)n * 256);
    float aP = 0.f, aS = 0.f, aD = 0.f;
#pragma unroll 8
    for (int k4 = 0; k4 < 64; ++k4) {
        float4 f = f4[k4];
        int b = k4 * 32 + h;
        aP += f.x * Wl[b]        + f.y * Wl[b + 8]        + f.z * Wl[b + 16]        + f.w * Wl[b + 24];
        aS += f.x * Wl[2048 + b] + f.y * Wl[2048 + b + 8] + f.z * Wl[2048 + b + 16] + f.w * Wl[2048 + b + 24];
        aD += f.x * Wl[4096 + b] + f.y * Wl[4096 + b + 8] + f.z * Wl[4096 + b + 16] + f.w * Wl[4096 + b + 24];
    }
    fc[gid] = aP; as_t[gid] = aS; ad_t[gid] = aD;
}

// ---------------------------------------------------------------------------
// Edge attention value (8 lanes per edge, lane = head)
// ---------------------------------------------------------------------------
__device__ __forceinline__ float edge_ex(
    const float* __restrict__ feat_edge, const float* Wl,
    const float* __restrict__ as_t, const float* __restrict__ ad_t,
    int e, int h, int s, int d)
{
    const float4* fe = (const float4*)(feat_edge + (size_t)e * 16);
    float4 f0 = fe[0], f1 = fe[1], f2 = fe[2], f3 = fe[3];
    float ae = f0.x * Wl[h]      + f0.y * Wl[h + 8]   + f0.z * Wl[h + 16]  + f0.w * Wl[h + 24]
             + f1.x * Wl[h + 32] + f1.y * Wl[h + 40]  + f1.z * Wl[h + 48]  + f1.w * Wl[h + 56]
             + f2.x * Wl[h + 64] + f2.y * Wl[h + 72]  + f2.z * Wl[h + 80]  + f2.w * Wl[h + 88]
             + f3.x * Wl[h + 96] + f3.y * Wl[h + 104] + f3.z * Wl[h + 112] + f3.w * Wl[h + 120];
    float ev = as_t[(size_t)s * 8 + h] + ad_t[(size_t)d * 8 + h] + ae;
    ev = LRELU(ev);
    return __expf(ev);
}

// ---------------------------------------------------------------------------
// Pass 1: ex once per (edge,head); cache bf16 to exd; fp32 device atomics
// into softmax sum tables (8 same-row lanes merge to one 32B sector/table).
// ---------------------------------------------------------------------------
__global__ __launch_bounds__(256) void k_edge1(
    const float* __restrict__ feat_edge,
    const int* __restrict__ src, const int* __restrict__ dst,
    const float* __restrict__ We,
    const float* __restrict__ as_t, const float* __restrict__ ad_t,
    float* __restrict__ sum_dst, float* __restrict__ sum_src,
    unsigned short* __restrict__ exd, int E)
{
    __shared__ float Wl[128];
    if (threadIdx.x < 128) Wl[threadIdx.x] = We[threadIdx.x];
    __syncthreads();
    int gid = blockIdx.x * 256 + threadIdx.x;
    int e = gid >> 3, h = gid & 7;
    if (e >= E) return;
    int s = src[e], d = dst[e];
    float ex = edge_ex(feat_edge, Wl, as_t, ad_t, e, h, s, d);
    exd[gid] = f2bf(ex);
    atomicAdd(&sum_dst[(size_t)d * 8 + h], ex);
    atomicAdd(&sum_src[(size_t)s * 8 + h], ex);
}

// ---------------------------------------------------------------------------
// Pass 2: reload cached ex, normalize (dual softmax, geometric mean),
// accumulate msg in fp32 (1 atomic sector per edge).
// ---------------------------------------------------------------------------
__global__ __launch_bounds__(256) void k_edge2(
    const unsigned short* __restrict__ exd,
    const int* __restrict__ src, const int* __restrict__ dst,
    const float* __restrict__ sum_dst, const float* __restrict__ sum_src,
    const float* __restrict__ fc, float* __restrict__ msg, int E)
{
    int gid = blockIdx.x * 256 + threadIdx.x;
    int e = gid >> 3, h = gid & 7;
    if (e >= E) return;
    int s = src[e], d = dst[e];
    float ex = bf2f(exd[gid]);
    float Sd = sum_dst[(size_t)d * 8 + h];
    float Ss = sum_src[(size_t)s * 8 + h];
    float a_d = fmaxf(ex / Sd, 1e-9f);
    float a_s = fmaxf(ex / Ss, 1e-9f);
    atomicAdd(&msg[(size_t)d * 8 + h], fc[(size_t)s * 8 + h] * sqrtf(a_d * a_s));
}

// ---------------------------------------------------------------------------
// BatchNorm statistics: accum[0..7] = sum_h, accum[8..15] = sumsq_h
// ---------------------------------------------------------------------------
__global__ __launch_bounds__(256) void k_bn_stats(
    const float* __restrict__ msg, float* __restrict__ accum, int N)
{
    __shared__ float s1[8], s2[8];
    if (threadIdx.x < 8) { s1[threadIdx.x] = 0.f; s2[threadIdx.x] = 0.f; }
    __syncthreads();
    int h = threadIdx.x & 7;
    float a1 = 0.f, a2 = 0.f;
    int total = N * 8;
    for (int i = blockIdx.x * 256 + threadIdx.x; i < total; i += gridDim.x * 256) {
        float x = msg[i];
        a1 += x; a2 += x * x;
    }
    atomicAdd(&s1[h], a1);
    atomicAdd(&s2[h], a2);
    __syncthreads();
    if (threadIdx.x < 8) {
        atomicAdd(&accum[threadIdx.x], s1[threadIdx.x]);
        atomicAdd(&accum[8 + threadIdx.x], s2[threadIdx.x]);
    }
}

// ---------------------------------------------------------------------------
// Fused MFMA kernel (BN folded into h staging):
//   h   = BN(msg) * gamma + beta                [from accum stats]
//   rst = LRELU( feat@W1 + h@Wagg + bias1 )     [GEMM1, K=288 bf16 MFMA]
//   out = rst@W2 + bias2                        [GEMM2, K=256, rst in LDS]
// ---------------------------------------------------------------------------
#define ASTRIDE 296   // 288 K + 8 pad (bf16) -> 2-way (free) LDS conflicts

__global__ __launch_bounds__(256, 2) void k_fused_apply(
    const float* __restrict__ feat, const float* __restrict__ msg,
    const float* __restrict__ accum,
    const float* __restrict__ gamma, const float* __restrict__ beta,
    const unsigned short* __restrict__ B1t,
    const unsigned short* __restrict__ B2t,
    const float* __restrict__ bias1, const float* __restrict__ bias2,
    float* __restrict__ out, int N)
{
    __shared__ __align__(16) unsigned short As[64 * ASTRIDE];
    __shared__ __align__(16) unsigned short Bs[8192];

    int tid = threadIdx.x;
    int row0 = blockIdx.x * 64;

#pragma unroll
    for (int t = 0; t < 16; ++t) {
        int i = tid + t * 256;
        int r = i >> 6, k4 = i & 63;
        float4 f = make_float4(0.f, 0.f, 0.f, 0.f);
        if (row0 + r < N)
            f = ((const float4*)(feat + (size_t)(row0 + r) * 256))[k4];
        ushort4 b;
        b.x = f2bf(f.x); b.y = f2bf(f.y); b.z = f2bf(f.z); b.w = f2bf(f.w);
        *(ushort4*)&As[r * ASTRIDE + k4 * 4] = b;
    }
    // h staging with BN applied on the fly
#pragma unroll
    for (int t = 0; t < 8; ++t) {
        int e = tid + t * 256;
        int r = e >> 5, c = e & 31;
        float v = 0.f;
        if (c < 8 && row0 + r < N) {
            float invN = 1.0f / (float)N;
            float mu = accum[c] * invN;
            float var = accum[8 + c] * invN - mu * mu;
            float rstd = rsqrtf(var + 1e-5f);
            v = (msg[(size_t)(row0 + r) * 8 + c] - mu) * rstd * gamma[c] + beta[c];
        }
        As[r * ASTRIDE + 256 + c] = f2bf(v);
    }

    int wave = tid >> 6;
    int lane = tid & 63;
    int n16  = lane & 15;
    int quad = lane >> 4;
    int col0 = wave * 64;

    f32x4 acc[4][4];
#pragma unroll
    for (int rt = 0; rt < 4; ++rt)
#pragma unroll
        for (int ct = 0; ct < 4; ++ct)
            acc[rt][ct] = (f32x4){0.f, 0.f, 0.f, 0.f};

    for (int kc = 0; kc < 9; ++kc) {
        __syncthreads();
#pragma unroll
        for (int t = 0; t < 4; ++t) {
            int i = tid + t * 256;
            ((float4*)Bs)[i] = ((const float4*)(B1t + kc * 8192))[i];
        }
        __syncthreads();
        int kbase = kc * 32;
        short8 af[4], bf[4];
#pragma unroll
        for (int rt = 0; rt < 4; ++rt)
            af[rt] = *(const short8*)&As[(rt * 16 + n16) * ASTRIDE + kbase + quad * 8];
#pragma unroll
        for (int ct = 0; ct < 4; ++ct)
            bf[ct] = *(const short8*)&Bs[(col0 + ct * 16 + n16) * 32 + quad * 8];
#pragma unroll
        for (int rt = 0; rt < 4; ++rt)
#pragma unroll
            for (int ct = 0; ct < 4; ++ct)
                acc[rt][ct] = __builtin_amdgcn_mfma_f32_16x16x32_bf16(
                    af[rt], bf[ct], acc[rt][ct], 0, 0, 0);
    }

    float bi[4];
#pragma unroll
    for (int ct = 0; ct < 4; ++ct) bi[ct] = bias1[col0 + ct * 16 + n16];
    __syncthreads();
#pragma unroll
    for (int rt = 0; rt < 4; ++rt)
#pragma unroll
        for (int ct = 0; ct < 4; ++ct)
#pragma unroll
            for (int r = 0; r < 4; ++r) {
                float v = acc[rt][ct][r] + bi[ct];
                v = LRELU(v);
                int row = rt * 16 + quad * 4 + r;
                int col = col0 + ct * 16 + n16;
                As[row * ASTRIDE + col] = f2bf(v);
            }

#pragma unroll
    for (int rt = 0; rt < 4; ++rt)
#pragma unroll
        for (int ct = 0; ct < 4; ++ct)
            acc[rt][ct] = (f32x4){0.f, 0.f, 0.f, 0.f};

    for (int kc = 0; kc < 8; ++kc) {
        __syncthreads();
#pragma unroll
        for (int t = 0; t < 4; ++t) {
            int i = tid + t * 256;
            ((float4*)Bs)[i] = ((const float4*)(B2t + kc * 8192))[i];
        }
        __syncthreads();
        int kbase = kc * 32;
        short8 af[4], bf[4];
#pragma unroll
        for (int rt = 0; rt < 4; ++rt)
            af[rt] = *(const short8*)&As[(rt * 16 + n16) * ASTRIDE + kbase + quad * 8];
#pragma unroll
        for (int ct = 0; ct < 4; ++ct)
            bf[ct] = *(const short8*)&Bs[(col0 + ct * 16 + n16) * 32 + quad * 8];
#pragma unroll
        for (int rt = 0; rt < 4; ++rt)
#pragma unroll
            for (int ct = 0; ct < 4; ++ct)
                acc[rt][ct] = __builtin_amdgcn_mfma_f32_16x16x32_bf16(
                    af[rt], bf[ct], acc[rt][ct], 0, 0, 0);
    }

    float bi2[4];
#pragma unroll
    for (int ct = 0; ct < 4; ++ct) bi2[ct] = bias2[col0 + ct * 16 + n16];
#pragma unroll
    for (int rt = 0; rt < 4; ++rt)
#pragma unroll
        for (int r = 0; r < 4; ++r) {
            int row = row0 + rt * 16 + quad * 4 + r;
            if (row < N) {
#pragma unroll
                for (int ct = 0; ct < 4; ++ct) {
                    int col = col0 + ct * 16 + n16;
                    out[(size_t)row * 256 + col] = acc[rt][ct][r] + bi2[ct];
                }
            }
        }
}

// ---------------------------------------------------------------------------
extern "C" void kernel_launch(void* const* d_in, const int* in_sizes, int n_in,
                              void* d_out, int out_size, void* d_ws, size_t ws_size,
                              hipStream_t stream)
{
    const float* feat      = (const float*)d_in[0];
    const float* feat_edge = (const float*)d_in[1];
    const int*   src       = (const int*)d_in[2];
    const int*   dst       = (const int*)d_in[3];
    const float* W_prop    = (const float*)d_in[4];
    const float* W_as      = (const float*)d_in[5];
    const float* W_ad      = (const float*)d_in[6];
    const float* W_edge    = (const float*)d_in[7];
    const float* bn_gamma  = (const float*)d_in[8];
    const float* bn_beta   = (const float*)d_in[9];
    const float* W_agg     = (const float*)d_in[10];
    const float* b_agg     = (const float*)d_in[11];
    const float* W1        = (const float*)d_in[12];
    const float* b1        = (const float*)d_in[13];
    const float* W2        = (const float*)d_in[14];
    const float* b2        = (const float*)d_in[15];
    float* out = (float*)d_out;

    int N = in_sizes[0] / 256;
    int E = in_sizes[2];
    int N8 = N * 8;

    // ---- workspace layout (64B-aligned regions); zeroed prefix first ----
    char* base = (char*)d_ws;
    size_t o = 0;
    auto take = [&](size_t bytes) -> char* {
        char* p = base + o;
        o = (o + bytes + 63) & ~(size_t)63;
        return p;
    };
    float* sum_dst = (float*)take((size_t)N8 * sizeof(float));
    float* sum_src = (float*)take((size_t)N8 * sizeof(float));
    float* msg     = (float*)take((size_t)N8 * sizeof(float));
    float* accum   = (float*)take(16 * sizeof(float));
    size_t zero_bytes = o;                       // everything above needs zeroing
    float* fc    = (float*)take((size_t)N8 * sizeof(float));
    float* as_t  = (float*)take((size_t)N8 * sizeof(float));
    float* ad_t  = (float*)take((size_t)N8 * sizeof(float));
    float* bias1 = (float*)take(256 * sizeof(float));
    float* bias2 = (float*)take(256 * sizeof(float));
    unsigned short* B1t = (unsigned short*)take(73728 * sizeof(unsigned short));
    unsigned short* B2t = (unsigned short*)take(65536 * sizeof(unsigned short));
    unsigned short* exd = (unsigned short*)take((size_t)E * 8 * sizeof(unsigned short));
    (void)ws_size;   // total ~73 MB; round-5 run proved >= ~160 MB available

    hipMemsetAsync(d_ws, 0, zero_bytes, stream);

    int gridN8 = (N8 + 255) / 256;
    int gridE8 = (E * 8 + 255) / 256;
    int gridF  = (N + 63) / 64;

    k_nodeprep<<<gridN8 + 546, 256, 0, stream>>>(
        feat, W_prop, W_as, W_ad, fc, as_t, ad_t, N, gridN8,
        W1, W_agg, W2, b_agg, b1, b2, B1t, B2t, bias1, bias2);
    k_edge1<<<gridE8, 256, 0, stream>>>(feat_edge, src, dst, W_edge,
                                        as_t, ad_t, sum_dst, sum_src, exd, E);
    k_edge2<<<gridE8, 256, 0, stream>>>(exd, src, dst, sum_dst, sum_src,
                                        fc, msg, E);
    k_bn_stats<<<512, 256, 0, stream>>>(msg, accum, N);
    k_fused_apply<<<gridF, 256, 0, stream>>>(feat, msg, accum, bn_gamma, bn_beta,
                                             B1t, B2t, bias1, bias2, out, N);
}

// Round 7
// 969.350 us; speedup vs baseline: 4.4565x; 1.0010x over previous
//
#include <hip/hip_runtime.h>

#define LRELU(x) ((x) >= 0.0f ? (x) : 0.2f * (x))

typedef __attribute__((ext_vector_type(8))) short short8;
typedef __attribute__((ext_vector_type(4))) float f32x4;

__device__ __forceinline__ unsigned short f2bf(float f) {
    union { float f; unsigned int u; } v; v.f = f;
    unsigned int u = v.u;
    u += 0x7FFFu + ((u >> 16) & 1u);   // round-to-nearest-even
    return (unsigned short)(u >> 16);
}

__device__ __forceinline__ float bf2f(unsigned short u) {
    union { unsigned int u; float f; } v; v.u = ((unsigned int)u) << 16;
    return v.f;
}

// ---------------------------------------------------------------------------
// Merged K1: blocks [0, gridN8) compute node tables (fc/as/ad = feat @ W*),
// blocks [gridN8, gridN8+546) build bf16 weight tables + biases.
// ---------------------------------------------------------------------------
__global__ __launch_bounds__(256) void k_nodeprep(
    const float* __restrict__ feat,
    const float* __restrict__ Wp, const float* __restrict__ Was,
    const float* __restrict__ Wad,
    float* __restrict__ fc, float* __restrict__ as_t, float* __restrict__ ad_t,
    int N, int gridN8,
    const float* __restrict__ W1, const float* __restrict__ Wagg,
    const float* __restrict__ W2,
    const float* __restrict__ b_agg, const float* __restrict__ b1,
    const float* __restrict__ b2,
    unsigned short* __restrict__ B1t, unsigned short* __restrict__ B2t,
    float* __restrict__ bias1, float* __restrict__ bias2)
{
    if ((int)blockIdx.x >= gridN8) {
        int idx = (blockIdx.x - gridN8) * 256 + threadIdx.x;
        if (idx < 73728) {                       // 9 chunks * 8192
            int c = idx >> 13, rem = idx & 8191;
            int n = rem >> 5, k = rem & 31;
            float v;
            if (c < 8) v = W1[(c * 32 + k) * 256 + n];
            else       v = (k < 8) ? Wagg[k * 256 + n] : 0.f;
            B1t[idx] = f2bf(v);
        } else if (idx < 139264) {               // + 8 chunks * 8192
            int j = idx - 73728;
            int c = j >> 13, rem = j & 8191;
            int n = rem >> 5, k = rem & 31;
            B2t[j] = f2bf(W2[(c * 32 + k) * 256 + n]);
        } else if (idx < 139520) {
            int n = idx - 139264;
            bias1[n] = b_agg[n] + b1[n];
        } else if (idx < 139776) {
            int n = idx - 139520;
            bias2[n] = b2[n];
        }
        return;
    }
    __shared__ float Wl[3 * 2048];  // 3 x [256][8]
    for (int i = threadIdx.x; i < 3 * 2048; i += 256) {
        float v;
        if (i < 2048)      v = Wp[i];
        else if (i < 4096) v = Was[i - 2048];
        else               v = Wad[i - 4096];
        Wl[i] = v;
    }
    __syncthreads();
    int gid = blockIdx.x * 256 + threadIdx.x;
    int n = gid >> 3, h = gid & 7;
    if (n >= N) return;
    const float4* f4 = (const float4*)(feat + (size_t)n * 256);
    float aP = 0.f, aS = 0.f, aD = 0.f;
#pragma unroll 8
    for (int k4 = 0; k4 < 64; ++k4) {
        float4 f = f4[k4];
        int b = k4 * 32 + h;
        aP += f.x * Wl[b]        + f.y * Wl[b + 8]        + f.z * Wl[b + 16]        + f.w * Wl[b + 24];
        aS += f.x * Wl[2048 + b] + f.y * Wl[2048 + b + 8] + f.z * Wl[2048 + b + 16] + f.w * Wl[2048 + b + 24];
        aD += f.x * Wl[4096 + b] + f.y * Wl[4096 + b + 8] + f.z * Wl[4096 + b + 16] + f.w * Wl[4096 + b + 24];
    }
    fc[gid] = aP; as_t[gid] = aS; ad_t[gid] = aD;
}

// ---------------------------------------------------------------------------
// Edge attention value (8 lanes per edge, lane = head)
// ---------------------------------------------------------------------------
__device__ __forceinline__ float edge_ex(
    const float* __restrict__ feat_edge, const float* Wl,
    const float* __restrict__ as_t, const float* __restrict__ ad_t,
    int e, int h, int s, int d)
{
    const float4* fe = (const float4*)(feat_edge + (size_t)e * 16);
    float4 f0 = fe[0], f1 = fe[1], f2 = fe[2], f3 = fe[3];
    float ae = f0.x * Wl[h]      + f0.y * Wl[h + 8]   + f0.z * Wl[h + 16]  + f0.w * Wl[h + 24]
             + f1.x * Wl[h + 32] + f1.y * Wl[h + 40]  + f1.z * Wl[h + 48]  + f1.w * Wl[h + 56]
             + f2.x * Wl[h + 64] + f2.y * Wl[h + 72]  + f2.z * Wl[h + 80]  + f2.w * Wl[h + 88]
             + f3.x * Wl[h + 96] + f3.y * Wl[h + 104] + f3.z * Wl[h + 112] + f3.w * Wl[h + 120];
    float ev = as_t[(size_t)s * 8 + h] + ad_t[(size_t)d * 8 + h] + ae;
    ev = LRELU(ev);
    return __expf(ev);
}

// ---------------------------------------------------------------------------
// Pass 1: ex once per (edge,head); cache bf16 to exd; fp32 device atomics
// into softmax sum tables (8 same-row lanes merge to one 32B sector/table).
// ---------------------------------------------------------------------------
__global__ __launch_bounds__(256) void k_edge1(
    const float* __restrict__ feat_edge,
    const int* __restrict__ src, const int* __restrict__ dst,
    const float* __restrict__ We,
    const float* __restrict__ as_t, const float* __restrict__ ad_t,
    float* __restrict__ sum_dst, float* __restrict__ sum_src,
    unsigned short* __restrict__ exd, int E)
{
    __shared__ float Wl[128];
    if (threadIdx.x < 128) Wl[threadIdx.x] = We[threadIdx.x];
    __syncthreads();
    int gid = blockIdx.x * 256 + threadIdx.x;
    int e = gid >> 3, h = gid & 7;
    if (e >= E) return;
    int s = src[e], d = dst[e];
    float ex = edge_ex(feat_edge, Wl, as_t, ad_t, e, h, s, d);
    exd[gid] = f2bf(ex);
    atomicAdd(&sum_dst[(size_t)d * 8 + h], ex);
    atomicAdd(&sum_src[(size_t)s * 8 + h], ex);
}

// ---------------------------------------------------------------------------
// g[s][h] = fc[s][h] / sqrt(sum_src[s][h])   (degree-0 rows never read)
// ---------------------------------------------------------------------------
__global__ __launch_bounds__(256) void k_gtab(
    const float* __restrict__ fc, const float* __restrict__ sum_src,
    float* __restrict__ g, int total)
{
    int i = blockIdx.x * 256 + threadIdx.x;
    if (i >= total) return;
    g[i] = fc[i] * rsqrtf(fmaxf(sum_src[i], 1e-30f));
}

// ---------------------------------------------------------------------------
// Pass 2: U[d][h] += ex * g[s][h]   (1 gather + 1 atomic sector per edge)
//   msg[d] = U[d]/sqrt(Sd[d]) is applied later in k_bn_msg.
//   Uses sqrt(a_d*a_s) = ex/sqrt(Sd*Ss); the 1e-9 clip only binds for
//   contributions < ~3e-5*|fc| -- negligible vs bf16 tolerance.
// ---------------------------------------------------------------------------
__global__ __launch_bounds__(256) void k_edge2(
    const unsigned short* __restrict__ exd,
    const int* __restrict__ src, const int* __restrict__ dst,
    const float* __restrict__ g, float* __restrict__ U, int E)
{
    int gid = blockIdx.x * 256 + threadIdx.x;
    int e = gid >> 3, h = gid & 7;
    if (e >= E) return;
    int s = src[e], d = dst[e];
    float ex = bf2f(exd[gid]);
    atomicAdd(&U[(size_t)d * 8 + h], ex * g[(size_t)s * 8 + h]);
}

// ---------------------------------------------------------------------------
// msg = U * rsqrt(sum_dst) (in-place) + BatchNorm statistics
//   accum[0..7] = sum_h, accum[8..15] = sumsq_h
// ---------------------------------------------------------------------------
__global__ __launch_bounds__(256) void k_bn_msg(
    float* __restrict__ msg, const float* __restrict__ sum_dst,
    float* __restrict__ accum, int N)
{
    __shared__ float s1[8], s2[8];
    if (threadIdx.x < 8) { s1[threadIdx.x] = 0.f; s2[threadIdx.x] = 0.f; }
    __syncthreads();
    int h = threadIdx.x & 7;
    float a1 = 0.f, a2 = 0.f;
    int total = N * 8;
    for (int i = blockIdx.x * 256 + threadIdx.x; i < total; i += gridDim.x * 256) {
        float m = msg[i] * rsqrtf(fmaxf(sum_dst[i], 1e-30f));
        msg[i] = m;
        a1 += m; a2 += m * m;
    }
    atomicAdd(&s1[h], a1);
    atomicAdd(&s2[h], a2);
    __syncthreads();
    if (threadIdx.x < 8) {
        atomicAdd(&accum[threadIdx.x], s1[threadIdx.x]);
        atomicAdd(&accum[8 + threadIdx.x], s2[threadIdx.x]);
    }
}

// ---------------------------------------------------------------------------
// Fused MFMA kernel (BN folded into h staging):
//   h   = BN(msg) * gamma + beta                [from accum stats]
//   rst = LRELU( feat@W1 + h@Wagg + bias1 )     [GEMM1, K=288 bf16 MFMA]
//   out = rst@W2 + bias2                        [GEMM2, K=256, rst in LDS]
// ---------------------------------------------------------------------------
#define ASTRIDE 296   // 288 K + 8 pad (bf16) -> 2-way (free) LDS conflicts

__global__ __launch_bounds__(256, 2) void k_fused_apply(
    const float* __restrict__ feat, const float* __restrict__ msg,
    const float* __restrict__ accum,
    const float* __restrict__ gamma, const float* __restrict__ beta,
    const unsigned short* __restrict__ B1t,
    const unsigned short* __restrict__ B2t,
    const float* __restrict__ bias1, const float* __restrict__ bias2,
    float* __restrict__ out, int N)
{
    __shared__ __align__(16) unsigned short As[64 * ASTRIDE];
    __shared__ __align__(16) unsigned short Bs[8192];

    int tid = threadIdx.x;
    int row0 = blockIdx.x * 64;

#pragma unroll
    for (int t = 0; t < 16; ++t) {
        int i = tid + t * 256;
        int r = i >> 6, k4 = i & 63;
        float4 f = make_float4(0.f, 0.f, 0.f, 0.f);
        if (row0 + r < N)
            f = ((const float4*)(feat + (size_t)(row0 + r) * 256))[k4];
        ushort4 b;
        b.x = f2bf(f.x); b.y = f2bf(f.y); b.z = f2bf(f.z); b.w = f2bf(f.w);
        *(ushort4*)&As[r * ASTRIDE + k4 * 4] = b;
    }
    // h staging with BN applied on the fly
#pragma unroll
    for (int t = 0; t < 8; ++t) {
        int e = tid + t * 256;
        int r = e >> 5, c = e & 31;
        float v = 0.f;
        if (c < 8 && row0 + r < N) {
            float invN = 1.0f / (float)N;
            float mu = accum[c] * invN;
            float var = accum[8 + c] * invN - mu * mu;
            float rstd = rsqrtf(var + 1e-5f);
            v = (msg[(size_t)(row0 + r) * 8 + c] - mu) * rstd * gamma[c] + beta[c];
        }
        As[r * ASTRIDE + 256 + c] = f2bf(v);
    }

    int wave = tid >> 6;
    int lane = tid & 63;
    int n16  = lane & 15;
    int quad = lane >> 4;
    int col0 = wave * 64;

    f32x4 acc[4][4];
#pragma unroll
    for (int rt = 0; rt < 4; ++rt)
#pragma unroll
        for (int ct = 0; ct < 4; ++ct)
            acc[rt][ct] = (f32x4){0.f, 0.f, 0.f, 0.f};

    for (int kc = 0; kc < 9; ++kc) {
        __syncthreads();
#pragma unroll
        for (int t = 0; t < 4; ++t) {
            int i = tid + t * 256;
            ((float4*)Bs)[i] = ((const float4*)(B1t + kc * 8192))[i];
        }
        __syncthreads();
        int kbase = kc * 32;
        short8 af[4], bf[4];
#pragma unroll
        for (int rt = 0; rt < 4; ++rt)
            af[rt] = *(const short8*)&As[(rt * 16 + n16) * ASTRIDE + kbase + quad * 8];
#pragma unroll
        for (int ct = 0; ct < 4; ++ct)
            bf[ct] = *(const short8*)&Bs[(col0 + ct * 16 + n16) * 32 + quad * 8];
#pragma unroll
        for (int rt = 0; rt < 4; ++rt)
#pragma unroll
            for (int ct = 0; ct < 4; ++ct)
                acc[rt][ct] = __builtin_amdgcn_mfma_f32_16x16x32_bf16(
                    af[rt], bf[ct], acc[rt][ct], 0, 0, 0);
    }

    float bi[4];
#pragma unroll
    for (int ct = 0; ct < 4; ++ct) bi[ct] = bias1[col0 + ct * 16 + n16];
    __syncthreads();
#pragma unroll
    for (int rt = 0; rt < 4; ++rt)
#pragma unroll
        for (int ct = 0; ct < 4; ++ct)
#pragma unroll
            for (int r = 0; r < 4; ++r) {
                float v = acc[rt][ct][r] + bi[ct];
                v = LRELU(v);
                int row = rt * 16 + quad * 4 + r;
                int col = col0 + ct * 16 + n16;
                As[row * ASTRIDE + col] = f2bf(v);
            }

#pragma unroll
    for (int rt = 0; rt < 4; ++rt)
#pragma unroll
        for (int ct = 0; ct < 4; ++ct)
            acc[rt][ct] = (f32x4){0.f, 0.f, 0.f, 0.f};

    for (int kc = 0; kc < 8; ++kc) {
        __syncthreads();
#pragma unroll
        for (int t = 0; t < 4; ++t) {
            int i = tid + t * 256;
            ((float4*)Bs)[i] = ((const float4*)(B2t + kc * 8192))[i];
        }
        __syncthreads();
        int kbase = kc * 32;
        short8 af[4], bf[4];
#pragma unroll
        for (int rt = 0; rt < 4; ++rt)
            af[rt] = *(const short8*)&As[(rt * 16 + n16) * ASTRIDE + kbase + quad * 8];
#pragma unroll
        for (int ct = 0; ct < 4; ++ct)
            bf[ct] = *(const short8*)&Bs[(col0 + ct * 16 + n16) * 32 + quad * 8];
#pragma unroll
        for (int rt = 0; rt < 4; ++rt)
#pragma unroll
            for (int ct = 0; ct < 4; ++ct)
                acc[rt][ct] = __builtin_amdgcn_mfma_f32_16x16x32_bf16(
                    af[rt], bf[ct], acc[rt][ct], 0, 0, 0);
    }

    float bi2[4];
#pragma unroll
    for (int ct = 0; ct < 4; ++ct) bi2[ct] = bias2[col0 + ct * 16 + n16];
#pragma unroll
    for (int rt = 0; rt < 4; ++rt)
#pragma unroll
        for (int r = 0; r < 4; ++r) {
            int row = row0 + rt * 16 + quad * 4 + r;
            if (row < N) {
#pragma unroll
                for (int ct = 0; ct < 4; ++ct) {
                    int col = col0 + ct * 16 + n16;
                    out[(size_t)row * 256 + col] = acc[rt][ct][r] + bi2[ct];
                }
            }
        }
}

// ---------------------------------------------------------------------------
extern "C" void kernel_launch(void* const* d_in, const int* in_sizes, int n_in,
                              void* d_out, int out_size, void* d_ws, size_t ws_size,
                              hipStream_t stream)
{
    const float* feat      = (const float*)d_in[0];
    const float* feat_edge = (const float*)d_in[1];
    const int*   src       = (const int*)d_in[2];
    const int*   dst       = (const int*)d_in[3];
    const float* W_prop    = (const float*)d_in[4];
    const float* W_as      = (const float*)d_in[5];
    const float* W_ad      = (const float*)d_in[6];
    const float* W_edge    = (const float*)d_in[7];
    const float* bn_gamma  = (const float*)d_in[8];
    const float* bn_beta   = (const float*)d_in[9];
    const float* W_agg     = (const float*)d_in[10];
    const float* b_agg     = (const float*)d_in[11];
    const float* W1        = (const float*)d_in[12];
    const float* b1        = (const float*)d_in[13];
    const float* W2        = (const float*)d_in[14];
    const float* b2        = (const float*)d_in[15];
    float* out = (float*)d_out;

    int N = in_sizes[0] / 256;
    int E = in_sizes[2];
    int N8 = N * 8;

    // ---- workspace layout (64B-aligned regions); zeroed prefix first ----
    char* base = (char*)d_ws;
    size_t o = 0;
    auto take = [&](size_t bytes) -> char* {
        char* p = base + o;
        o = (o + bytes + 63) & ~(size_t)63;
        return p;
    };
    float* sum_dst = (float*)take((size_t)N8 * sizeof(float));
    float* sum_src = (float*)take((size_t)N8 * sizeof(float));
    float* msg     = (float*)take((size_t)N8 * sizeof(float));   // U, then msg
    float* accum   = (float*)take(16 * sizeof(float));
    size_t zero_bytes = o;                       // everything above needs zeroing
    float* fc    = (float*)take((size_t)N8 * sizeof(float));
    float* as_t  = (float*)take((size_t)N8 * sizeof(float));
    float* ad_t  = (float*)take((size_t)N8 * sizeof(float));
    float* g     = (float*)take((size_t)N8 * sizeof(float));
    float* bias1 = (float*)take(256 * sizeof(float));
    float* bias2 = (float*)take(256 * sizeof(float));
    unsigned short* B1t = (unsigned short*)take(73728 * sizeof(unsigned short));
    unsigned short* B2t = (unsigned short*)take(65536 * sizeof(unsigned short));
    unsigned short* exd = (unsigned short*)take((size_t)E * 8 * sizeof(unsigned short));
    (void)ws_size;   // total ~76 MB; prior rounds proved >= ~160 MB available

    hipMemsetAsync(d_ws, 0, zero_bytes, stream);

    int gridN8 = (N8 + 255) / 256;
    int gridE8 = (E * 8 + 255) / 256;
    int gridF  = (N + 63) / 64;

    k_nodeprep<<<gridN8 + 546, 256, 0, stream>>>(
        feat, W_prop, W_as, W_ad, fc, as_t, ad_t, N, gridN8,
        W1, W_agg, W2, b_agg, b1, b2, B1t, B2t, bias1, bias2);
    k_edge1<<<gridE8, 256, 0, stream>>>(feat_edge, src, dst, W_edge,
                                        as_t, ad_t, sum_dst, sum_src, exd, E);
    k_gtab<<<gridN8, 256, 0, stream>>>(fc, sum_src, g, N8);
    k_edge2<<<gridE8, 256, 0, stream>>>(exd, src, dst, g, msg, E);
    k_bn_msg<<<512, 256, 0, stream>>>(msg, sum_dst, accum, N);
    k_fused_apply<<<gridF, 256, 0, stream>>>(feat, msg, accum, bn_gamma, bn_beta,
                                             B1t, B2t, bias1, bias2, out, N);
}